// Round 7
// baseline (520.900 us; speedup 1.0000x reference)
//
#include <hip/hip_runtime.h>
#include <cstdio>
#include <cstdint>

#define S_TOK 4096
#define CDIM  1024
#define EXP   8
#define HRAW  2744
#define HPAD  2816
#define MAXROWS  13312   // 104 tiles * 128
#define MAXTILES 104
#define NSLICE1  (HPAD / 128)   // 22
#define NSLICE2  (CDIM / 128)   // 8
#define NT1K     (CDIM / 64)    // 16 K-tiles of 64 for gemm1
#define NT2      (HPAD / 32)    // 88

typedef __attribute__((ext_vector_type(8))) short bf16x8;
typedef __attribute__((ext_vector_type(4))) float f32x4;
typedef __attribute__((ext_vector_type(4))) unsigned short us4;
typedef unsigned short us;

__device__ __forceinline__ us f2bf(float f) {
  unsigned u = __float_as_uint(f);
  u += 0x7fffu + ((u >> 16) & 1u);
  return (us)(u >> 16);
}

__device__ __forceinline__ void gl16(const us* g, us* l) {
  __builtin_amdgcn_global_load_lds((__attribute__((address_space(1))) void*)g,
                                   (__attribute__((address_space(3))) void*)l,
                                   16, 0, 0);
}

// bijective XCD swizzle (m204)
__device__ __forceinline__ int xcd_swz(int orig, int nwg) {
  int q = nwg >> 3, r = nwg & 7;
  int x = orig & 7, idx = orig >> 3;
  return (x < r ? x * (q + 1) : r * (q + 1) + (x - r) * q) + idx;
}

// ---------------- fused weight conversion (fp32 -> bf16, padded) ----------------
#define CH_RP1  (HPAD * CDIM / 4)
#define CH_CPR  (HPAD / 4)
#define R_W1    (8 * CH_RP1)
#define R_W2    (R_W1 + 8 * CH_RP1)
#define R_W3    (R_W2 + 8 * CDIM * CH_CPR)
#define R_SW1   (R_W3 + CH_RP1)
#define R_SW2   (R_SW1 + CH_RP1)
#define R_SW3   (R_SW2 + CDIM * CH_CPR)

__device__ __forceinline__ void cvt4_rowpad(const float* __restrict__ src,
                                            us* __restrict__ dst, int idx) {
  int m = idx / CH_RP1, rem = idx - m * CH_RP1;
  int r = rem >> 8, c4 = rem & 255;
  us4 o;
  if (r < HRAW) {
    float4 v = *(const float4*)(src + ((size_t)(m * HRAW + r) * CDIM + c4 * 4));
    o.x = f2bf(v.x); o.y = f2bf(v.y); o.z = f2bf(v.z); o.w = f2bf(v.w);
  } else { o.x = 0; o.y = 0; o.z = 0; o.w = 0; }
  *(us4*)(dst + ((size_t)(m * HPAD + r) * CDIM + c4 * 4)) = o;
}

__device__ __forceinline__ void cvt4_colpad(const float* __restrict__ src,
                                            us* __restrict__ dst, int idx) {
  int r = idx / CH_CPR, c4 = idx - r * CH_CPR;
  int c = c4 * 4;
  us4 o;
  if (c < HRAW) {
    float4 v = *(const float4*)(src + (size_t)r * HRAW + c);
    o.x = f2bf(v.x); o.y = f2bf(v.y); o.z = f2bf(v.z); o.w = f2bf(v.w);
  } else { o.x = 0; o.y = 0; o.z = 0; o.w = 0; }
  *(us4*)(dst + (size_t)r * HPAD + c) = o;
}

__global__ void __launch_bounds__(256) cvt_all_kernel(
    const float* __restrict__ w1, const float* __restrict__ w2,
    const float* __restrict__ w3, const float* __restrict__ sw1,
    const float* __restrict__ sw2, const float* __restrict__ sw3,
    us* __restrict__ w1b, us* __restrict__ w2b, us* __restrict__ w3b,
    us* __restrict__ sw1b, us* __restrict__ sw2b, us* __restrict__ sw3b) {
  for (int i = blockIdx.x * 256 + threadIdx.x; i < R_SW3; i += gridDim.x * 256) {
    if (i < R_W1)       cvt4_rowpad(w1,  w1b,  i);
    else if (i < R_W2)  cvt4_rowpad(w2,  w2b,  i - R_W1);
    else if (i < R_W3)  cvt4_colpad(w3,  w3b,  i - R_W2);
    else if (i < R_SW1) cvt4_rowpad(sw1, sw1b, i - R_W3);
    else if (i < R_SW2) cvt4_rowpad(sw2, sw2b, i - R_SW1);
    else                cvt4_colpad(sw3, sw3b, i - R_SW2);
  }
}

// ---------------- gating (NO atomics) ----------------
__global__ void __launch_bounds__(256) gate_kernel(const float* __restrict__ x,
                                                   const float* __restrict__ gw,
                                                   us* __restrict__ xb,
                                                   int* __restrict__ tki,
                                                   float* __restrict__ tkw,
                                                   float* __restrict__ probs) {
  const int wv = threadIdx.x >> 6, lane = threadIdx.x & 63;
  const int s = blockIdx.x * 4 + wv;
  const float4* xs4 = (const float4*)(x + (size_t)s * CDIM);
  float acc[8] = {0, 0, 0, 0, 0, 0, 0, 0};
#pragma unroll
  for (int j = 0; j < 4; j++) {
    float4 v = xs4[lane * 4 + j];
    int c = lane * 16 + j * 4;
    us4 ov;
    ov.x = f2bf(v.x); ov.y = f2bf(v.y); ov.z = f2bf(v.z); ov.w = f2bf(v.w);
    *(us4*)(xb + (size_t)s * CDIM + c) = ov;
#pragma unroll
    for (int ee = 0; ee < 8; ee++) {
      const float* g = gw + ee * CDIM + c;
      acc[ee] += v.x * g[0] + v.y * g[1] + v.z * g[2] + v.w * g[3];
    }
  }
#pragma unroll
  for (int ee = 0; ee < 8; ee++) {
#pragma unroll
    for (int off = 32; off > 0; off >>= 1) acc[ee] += __shfl_xor(acc[ee], off, 64);
  }
  if (lane == 0) {
    float mx = acc[0];
    for (int ee = 1; ee < 8; ee++) mx = fmaxf(mx, acc[ee]);
    float p[8], sm = 0.f;
    for (int ee = 0; ee < 8; ee++) { p[ee] = expf(acc[ee] - mx); sm += p[ee]; }
    float inv = 1.f / sm;
    for (int ee = 0; ee < 8; ee++) probs[s * 8 + ee] = p[ee] * inv;
    int i0 = 0; float b0 = p[0];
    for (int ee = 1; ee < 8; ee++) if (p[ee] > b0) { b0 = p[ee]; i0 = ee; }
    int i1 = -1; float b1 = -1.f;
    for (int ee = 0; ee < 8; ee++) if (ee != i0 && p[ee] > b1) { b1 = p[ee]; i1 = ee; }
    float rw0 = b0 * inv, rw1 = b1 * inv;
    float den = 1.f / (rw0 + rw1);
    tki[2 * s] = i0; tki[2 * s + 1] = i1;
    tkw[2 * s] = rw0 * den; tkw[2 * s + 1] = rw1 * den;
  }
}

// ---------------- counting + routing lists + inverse map + aux loss ----------------
__global__ void __launch_bounds__(512) build_kernel(const int* __restrict__ tki,
                                                    const float* __restrict__ tkw,
                                                    const float* __restrict__ probs,
                                                    int* __restrict__ meta,
                                                    int* __restrict__ pairtok,
                                                    float* __restrict__ pairw,
                                                    int* __restrict__ invmap,
                                                    int* __restrict__ tile_expert,
                                                    float* __restrict__ aux_out) {
  const int tid = threadIdx.x, lane = tid & 63, wv = tid >> 6;
  __shared__ int s_cnt[EXP];
  __shared__ int s_amc[EXP];
  __shared__ float s_imp[EXP];
  {
    const int e = wv;
    int c_cnt = 0, c_amc = 0;
    float imp = 0.f;
    for (int s0 = 0; s0 < S_TOK; s0 += 64) {
      int s = s0 + lane;
      int i0 = tki[2 * s], i1 = tki[2 * s + 1];
      c_cnt += (i0 == e) || (i1 == e);
      c_amc += (i0 == e);
      imp += probs[s * 8 + e];
    }
#pragma unroll
    for (int off = 32; off > 0; off >>= 1) {
      c_cnt += __shfl_xor(c_cnt, off, 64);
      c_amc += __shfl_xor(c_amc, off, 64);
      imp   += __shfl_xor(imp, off, 64);
    }
    if (lane == 0) { s_cnt[e] = c_cnt; s_amc[e] = c_amc; s_imp[e] = imp; }
  }
  __syncthreads();
  int pad[EXP], start[EXP];
  int o = S_TOK;
#pragma unroll
  for (int j = 0; j < EXP; j++) {
    pad[j] = ((s_cnt[j] + 127) >> 7) << 7;
    start[j] = o;
    o += pad[j];
  }
  const int total = o;
  for (int r = tid; r < S_TOK; r += 512) { pairtok[r] = r; pairw[r] = 1.f; }
  {
    const int e = wv;
    int base = start[e];
    for (int s0 = 0; s0 < S_TOK; s0 += 64) {
      int s = s0 + lane;
      int i0 = tki[2 * s], i1 = tki[2 * s + 1];
      bool m0 = (i0 == e), m1 = (i1 == e);
      bool mm = m0 || m1;
      unsigned long long mk = __ballot(mm);
      if (mm) {
        int pos = base + __popcll(mk & ((1ull << lane) - 1ull));
        pairtok[pos] = s;
        pairw[pos] = m0 ? tkw[2 * s] : tkw[2 * s + 1];
        invmap[2 * s + (m0 ? 0 : 1)] = pos;
      }
      base += __popcll(mk);
    }
    for (int r = base + lane; r < start[e] + pad[e]; r += 64) {
      pairtok[r] = -1; pairw[r] = 0.f;
    }
  }
  if (tid < 128) {
    int ex = 8;
    if (tid >= 32) {
      int rr = tid * 128;
#pragma unroll
      for (int j = 0; j < EXP; j++)
        if (rr >= start[j] && rr < start[j] + pad[j]) ex = j;
    }
    tile_expert[tid] = ex;
  }
  if (tid == 0) {
    meta[0] = total >> 7;
    float a = 0.f;
    for (int j = 0; j < EXP; j++)
      a += (s_imp[j] * (1.f / 4096.f)) * ((float)s_amc[j] * (1.f / 4096.f));
    aux_out[0] = 8.f * a;
  }
}

// ---------------- GEMM1: ring-3 counted-vmcnt pipeline ----------------
// 512 thr / 8 waves (wm 0..1 x wn 0..3); per-wave: u,v 64x32 patches.
// BK=64, 3-slot LDS ring (A,B1,B2 = 144KB). One s_barrier per K-tile;
// vmcnt(6) keeps the newest staged K-tile (6 loads/wave) in flight always.
// LDS swizzle: 128B rows -> physical octet = logical ^ (row&7), applied on
// BOTH the pre-swizzled global source and the ds_read address (rule 21).
__global__ void __launch_bounds__(512, 1) gemm1_kernel(
    const us* __restrict__ xb, const us* __restrict__ w1b, const us* __restrict__ w2b,
    const us* __restrict__ sw1b, const us* __restrict__ sw2b,
    const int* __restrict__ pairtok, const int* __restrict__ tile_expert,
    const int* __restrict__ meta, us* __restrict__ h) {
  const int wgid = xcd_swz(blockIdx.x, MAXTILES * NSLICE1);
  const int mt = wgid % MAXTILES;
  if (mt >= meta[0]) return;
  const int n0 = (wgid / MAXTILES) * 128;
  const int e = tile_expert[mt];
  const us* B1 = (e == 8) ? sw1b : (w1b + (size_t)e * HPAD * CDIM);
  const us* B2 = (e == 8) ? sw2b : (w2b + (size_t)e * HPAD * CDIM);
  const int row0 = mt * 128;
  __shared__ __align__(16) us sA[3][128 * 64];
  __shared__ __align__(16) us sB1[3][128 * 64];
  __shared__ __align__(16) us sB2[3][128 * 64];
  const int tid = threadIdx.x, lane = tid & 63, wid = tid >> 6;
  const int wm = wid >> 2, wn = wid & 3;
  // staging map: instr j of wave wid covers rows (wid*2+j)*8 + (lane>>3),
  // physical octet lane&7, fetched logical octet = (lane&7) ^ (row&7).
  const int srow0 = (wid * 2 + 0) * 8 + (lane >> 3);
  const int srow1 = (wid * 2 + 1) * 8 + (lane >> 3);
  const int soct0 = (lane & 7) ^ (srow0 & 7);
  const int soct1 = (lane & 7) ^ (srow1 & 7);
  const int ldst0 = (wid * 2 + 0) * 512 + lane * 8;
  const int ldst1 = (wid * 2 + 1) * 512 + lane * 8;
  int ta0 = pairtok[row0 + srow0]; if (ta0 < 0) ta0 = 0;
  int ta1 = pairtok[row0 + srow1]; if (ta1 < 0) ta1 = 0;
  const us* gA0  = xb + (size_t)ta0 * CDIM + soct0 * 8;
  const us* gA1  = xb + (size_t)ta1 * CDIM + soct1 * 8;
  const us* gB1a = B1 + (size_t)(n0 + srow0) * CDIM + soct0 * 8;
  const us* gB1b = B1 + (size_t)(n0 + srow1) * CDIM + soct1 * 8;
  const us* gB2a = B2 + (size_t)(n0 + srow0) * CDIM + soct0 * 8;
  const us* gB2b = B2 + (size_t)(n0 + srow1) * CDIM + soct1 * 8;

#define G1_STAGE(slot, k0)                  \
  do {                                      \
    gl16(gA0 + (k0),  &sA[slot][ldst0]);    \
    gl16(gA1 + (k0),  &sA[slot][ldst1]);    \
    gl16(gB1a + (k0), &sB1[slot][ldst0]);   \
    gl16(gB1b + (k0), &sB1[slot][ldst1]);   \
    gl16(gB2a + (k0), &sB2[slot][ldst0]);   \
    gl16(gB2b + (k0), &sB2[slot][ldst1]);   \
  } while (0)

  f32x4 au[4][2], av[4][2];
#pragma unroll
  for (int m = 0; m < 4; m++)
#pragma unroll
    for (int n = 0; n < 2; n++)
#pragma unroll
      for (int r = 0; r < 4; r++) { au[m][n][r] = 0.f; av[m][n][r] = 0.f; }

  // fragment read addresses (element offsets within a [128][64] slot)
  const int fr = lane & 15, fo = lane >> 4;   // frag row-in-16, octet-in-kstep
  int offA[4][2], offB[2][2];
#pragma unroll
  for (int m = 0; m < 4; m++)
#pragma unroll
    for (int ks = 0; ks < 2; ks++) {
      int row = wm * 64 + m * 16 + fr;
      int lo = ks * 4 + fo;
      offA[m][ks] = row * 64 + (lo ^ (row & 7)) * 8;
    }
#pragma unroll
  for (int n = 0; n < 2; n++)
#pragma unroll
    for (int ks = 0; ks < 2; ks++) {
      int row = wn * 32 + n * 16 + fr;
      int lo = ks * 4 + fo;
      offB[n][ks] = row * 64 + (lo ^ (row & 7)) * 8;
    }

  G1_STAGE(0, 0);
  G1_STAGE(1, 64);
#pragma unroll 1
  for (int t = 0; t < NT1K; t++) {
    __builtin_amdgcn_sched_barrier(0);
    __builtin_amdgcn_s_barrier();      // slot (t+2)%3 free; prior reads retired
    if (t + 2 < NT1K) G1_STAGE((t + 2) % 3, (t + 2) * 64);
    if (t < NT1K - 1) asm volatile("s_waitcnt vmcnt(6)" ::: "memory");
    else              asm volatile("s_waitcnt vmcnt(0)" ::: "memory");
    __builtin_amdgcn_sched_barrier(0);
    const us* pa  = sA[t % 3];
    const us* pb1 = sB1[t % 3];
    const us* pb2 = sB2[t % 3];
    bf16x8 a[4][2], b1[2][2], b2[2][2];
#pragma unroll
    for (int m = 0; m < 4; m++)
#pragma unroll
      for (int ks = 0; ks < 2; ks++)
        a[m][ks] = *(const bf16x8*)&pa[offA[m][ks]];
#pragma unroll
    for (int n = 0; n < 2; n++)
#pragma unroll
      for (int ks = 0; ks < 2; ks++) {
        b1[n][ks] = *(const bf16x8*)&pb1[offB[n][ks]];
        b2[n][ks] = *(const bf16x8*)&pb2[offB[n][ks]];
      }
#pragma unroll
    for (int ks = 0; ks < 2; ks++)
#pragma unroll
      for (int m = 0; m < 4; m++)
#pragma unroll
        for (int n = 0; n < 2; n++) {
          au[m][n] = __builtin_amdgcn_mfma_f32_16x16x32_bf16(a[m][ks], b1[n][ks], au[m][n], 0, 0, 0);
          av[m][n] = __builtin_amdgcn_mfma_f32_16x16x32_bf16(a[m][ks], b2[n][ks], av[m][n], 0, 0, 0);
        }
  }
#undef G1_STAGE
  const int rb = (lane >> 4) * 4, cb = lane & 15;
#pragma unroll
  for (int m = 0; m < 4; m++)
#pragma unroll
    for (int n = 0; n < 2; n++)
#pragma unroll
      for (int r = 0; r < 4; r++) {
        int row = row0 + wm * 64 + m * 16 + rb + r;
        int col = n0 + wn * 32 + n * 16 + cb;
        float u = au[m][n][r], v = av[m][n][r];
        float sg = 1.f / (1.f + __expf(-u));
        h[(size_t)row * HPAD + col] = f2bf(u * sg * v);
      }
}

// ---------------- GEMM2: eo[slot] = h @ w3^T (round-6 structure) -------
__global__ void __launch_bounds__(256, 2) gemm2_kernel(
    const us* __restrict__ h, const us* __restrict__ w3b, const us* __restrict__ sw3b,
    const int* __restrict__ tile_expert, const int* __restrict__ meta,
    float* __restrict__ eo) {
  const int wgid = xcd_swz(blockIdx.x, MAXTILES * NSLICE2);
  const int mt = wgid % MAXTILES;
  if (mt >= meta[0]) return;
  const int n0 = (wgid / MAXTILES) * 128;
  const int e = tile_expert[mt];
  const us* B = (e == 8) ? sw3b : (w3b + (size_t)e * CDIM * HPAD);
  const int row0 = mt * 128;
  __shared__ __align__(16) us sA[128 * 32];
  __shared__ __align__(16) us sB[128 * 32];
  const int tid = threadIdx.x, lane = tid & 63;
  const int wm = tid >> 7, wn = (tid >> 6) & 1;
  const int sub = tid & 3, ra = tid >> 2;
  const int subx = sub ^ ((ra >> 1) & 3);
  const us* gA0 = h + (size_t)(row0 + ra) * HPAD + subx * 8;
  const us* gA1 = h + (size_t)(row0 + 64 + ra) * HPAD + subx * 8;
  const us* gB0 = B + (size_t)(n0 + ra) * HPAD + subx * 8;
  const us* gB1 = B + (size_t)(n0 + 64 + ra) * HPAD + subx * 8;
  f32x4 ac[4][4];
#pragma unroll
  for (int m = 0; m < 4; m++)
#pragma unroll
    for (int n = 0; n < 4; n++)
#pragma unroll
      for (int r = 0; r < 4; r++) ac[m][n][r] = 0.f;

  const int rl = lane & 15;
  const int kx = (((lane >> 4) ^ ((lane >> 1) & 3)) << 3);
  for (int k0 = 0; k0 < HPAD; k0 += 32) {
    gl16(gA0 + k0, &sA[tid * 8]);
    gl16(gA1 + k0, &sA[(tid + 256) * 8]);
    gl16(gB0 + k0, &sB[tid * 8]);
    gl16(gB1 + k0, &sB[(tid + 256) * 8]);
    __syncthreads();
    bf16x8 a[4], b[4];
#pragma unroll
    for (int m = 0; m < 4; m++)
      a[m] = *(const bf16x8*)&sA[(wm * 64 + m * 16 + rl) * 32 + kx];
#pragma unroll
    for (int n = 0; n < 4; n++)
      b[n] = *(const bf16x8*)&sB[(wn * 64 + n * 16 + rl) * 32 + kx];
#pragma unroll
    for (int m = 0; m < 4; m++)
#pragma unroll
      for (int n = 0; n < 4; n++)
        ac[m][n] = __builtin_amdgcn_mfma_f32_16x16x32_bf16(a[m], b[n], ac[m][n], 0, 0, 0);
    __syncthreads();
  }
  const int rb = (lane >> 4) * 4, cb = lane & 15;
#pragma unroll
  for (int m = 0; m < 4; m++)
#pragma unroll
    for (int n = 0; n < 4; n++)
#pragma unroll
      for (int r = 0; r < 4; r++) {
        int row = row0 + wm * 64 + m * 16 + rb + r;
        int col = n0 + wn * 64 + n * 16 + cb;
        eo[(size_t)row * CDIM + col] = ac[m][n][r];
      }
}

// ---------------- combine ----------------
__global__ void __launch_bounds__(256) combine_kernel(const float* __restrict__ eo,
                                                      const int* __restrict__ invmap,
                                                      const float* __restrict__ pairw,
                                                      float* __restrict__ out) {
  const int s = blockIdx.x;
  const int c = threadIdx.x * 4;
  const int j0 = invmap[2 * s], j1 = invmap[2 * s + 1];
  const float w0 = pairw[j0], w1 = pairw[j1];
  float4 a = *(const float4*)(eo + (size_t)s * CDIM + c);
  float4 b = *(const float4*)(eo + (size_t)j0 * CDIM + c);
  float4 d = *(const float4*)(eo + (size_t)j1 * CDIM + c);
  float4 o;
  o.x = a.x + w0 * b.x + w1 * d.x;
  o.y = a.y + w0 * b.y + w1 * d.y;
  o.z = a.z + w0 * b.z + w1 * d.z;
  o.w = a.w + w0 * b.w + w1 * d.w;
  *(float4*)(out + (size_t)s * CDIM + c) = o;
}

extern "C" void kernel_launch(void* const* d_in, const int* in_sizes, int n_in,
                              void* d_out, int out_size, void* d_ws, size_t ws_size,
                              hipStream_t stream) {
  const float* x   = (const float*)d_in[0];
  const float* gw  = (const float*)d_in[1];
  const float* w1  = (const float*)d_in[2];
  const float* w2  = (const float*)d_in[3];
  const float* w3  = (const float*)d_in[4];
  const float* sw1 = (const float*)d_in[5];
  const float* sw2 = (const float*)d_in[6];
  const float* sw3 = (const float*)d_in[7];
  float* out = (float*)d_out;
  char* ws = (char*)d_ws;
  size_t off = 0;
  auto take = [&](size_t bytes) -> char* {
    char* p = ws + off;
    off = (off + bytes + 255) & ~(size_t)255;
    return p;
  };
  us* xb    = (us*)take((size_t)S_TOK * CDIM * 2);
  us* w1b   = (us*)take((size_t)EXP * HPAD * CDIM * 2);
  us* w2b   = (us*)take((size_t)EXP * HPAD * CDIM * 2);
  us* w3b   = (us*)take((size_t)EXP * CDIM * HPAD * 2);
  us* sw1b  = (us*)take((size_t)HPAD * CDIM * 2);
  us* sw2b  = (us*)take((size_t)HPAD * CDIM * 2);
  us* sw3b  = (us*)take((size_t)CDIM * HPAD * 2);
  us* hbuf  = (us*)take((size_t)MAXROWS * HPAD * 2);
  int* pairtok = (int*)take(MAXROWS * 4);
  float* pairw = (float*)take(MAXROWS * 4);
  int* invmap  = (int*)take(S_TOK * 2 * 4);
  int* tile_expert = (int*)take(128 * 4);
  int* tki = (int*)take(S_TOK * 2 * 4);
  float* tkw = (float*)take(S_TOK * 2 * 4);
  float* probs = (float*)take(S_TOK * EXP * 4);
  int* meta = (int*)take(256);
  float* eo = (float*)w1b;  // aliases w1b+w2b, dead after gemm1
  if (off > ws_size) {
    fprintf(stderr, "MoE kernel: ws too small, need %zu got %zu\n", off, ws_size);
    return;
  }
  cvt_all_kernel<<<2048, 256, 0, stream>>>(w1, w2, w3, sw1, sw2, sw3,
                                           w1b, w2b, w3b, sw1b, sw2b, sw3b);
  gate_kernel<<<S_TOK / 4, 256, 0, stream>>>(x, gw, xb, tki, tkw, probs);
  build_kernel<<<1, 512, 0, stream>>>(tki, tkw, probs, meta, pairtok, pairw, invmap,
                                      tile_expert, out + (size_t)S_TOK * CDIM);
  gemm1_kernel<<<MAXTILES * NSLICE1, 512, 0, stream>>>(
      xb, w1b, w2b, sw1b, sw2b, pairtok, tile_expert, meta, hbuf);
  gemm2_kernel<<<MAXTILES * NSLICE2, 256, 0, stream>>>(
      hbuf, w3b, sw3b, tile_expert, meta, eo);
  combine_kernel<<<S_TOK, 256, 0, stream>>>(eo, invmap, pairw, out);
}

// Round 8
// 472.032 us; speedup vs baseline: 1.1035x; 1.1035x over previous
//
#include <hip/hip_runtime.h>
#include <cstdio>
#include <cstdint>

#define S_TOK 4096
#define CDIM  1024
#define EXP   8
#define HRAW  2744
#define HPAD  2816
#define MAXROWS  13312   // 104 tiles * 128
#define MAXTILES 104
#define NSLICE1  (HPAD / 128)   // 22
#define NSLICE2  (CDIM / 256)   // 4  (gemm2 block = 128x256)

typedef __attribute__((ext_vector_type(8))) short bf16x8;
typedef __attribute__((ext_vector_type(4))) float f32x4;
typedef __attribute__((ext_vector_type(4))) unsigned short us4;
typedef unsigned short us;

__device__ __forceinline__ us f2bf(float f) {
  unsigned u = __float_as_uint(f);
  u += 0x7fffu + ((u >> 16) & 1u);
  return (us)(u >> 16);
}

__device__ __forceinline__ void gl16(const us* g, us* l) {
  __builtin_amdgcn_global_load_lds((__attribute__((address_space(1))) void*)g,
                                   (__attribute__((address_space(3))) void*)l,
                                   16, 0, 0);
}

// bijective XCD swizzle (m204)
__device__ __forceinline__ int xcd_swz(int orig, int nwg) {
  int q = nwg >> 3, r = nwg & 7;
  int x = orig & 7, idx = orig >> 3;
  return (x < r ? x * (q + 1) : r * (q + 1) + (x - r) * q) + idx;
}

// ---------------- fused cvt (fp32->bf16 padded) + gate ----------------
#define CH_RP1  (HPAD * CDIM / 4)
#define CH_CPR  (HPAD / 4)
#define R_W1    (8 * CH_RP1)
#define R_W2    (R_W1 + 8 * CH_RP1)
#define R_W3    (R_W2 + 8 * CDIM * CH_CPR)
#define R_SW1   (R_W3 + CH_RP1)
#define R_SW2   (R_SW1 + CH_RP1)
#define R_SW3   (R_SW2 + CDIM * CH_CPR)
#define GATE_BLKS (S_TOK / 4)   // 1024
#define CVT_BLKS  2048

__device__ __forceinline__ void cvt4_rowpad(const float* __restrict__ src,
                                            us* __restrict__ dst, int idx) {
  int m = idx / CH_RP1, rem = idx - m * CH_RP1;
  int r = rem >> 8, c4 = rem & 255;
  us4 o;
  if (r < HRAW) {
    float4 v = *(const float4*)(src + ((size_t)(m * HRAW + r) * CDIM + c4 * 4));
    o.x = f2bf(v.x); o.y = f2bf(v.y); o.z = f2bf(v.z); o.w = f2bf(v.w);
  } else { o.x = 0; o.y = 0; o.z = 0; o.w = 0; }
  *(us4*)(dst + ((size_t)(m * HPAD + r) * CDIM + c4 * 4)) = o;
}

__device__ __forceinline__ void cvt4_colpad(const float* __restrict__ src,
                                            us* __restrict__ dst, int idx) {
  int r = idx / CH_CPR, c4 = idx - r * CH_CPR;
  int c = c4 * 4;
  us4 o;
  if (c < HRAW) {
    float4 v = *(const float4*)(src + (size_t)r * HRAW + c);
    o.x = f2bf(v.x); o.y = f2bf(v.y); o.z = f2bf(v.z); o.w = f2bf(v.w);
  } else { o.x = 0; o.y = 0; o.z = 0; o.w = 0; }
  *(us4*)(dst + (size_t)r * HPAD + c) = o;
}

__global__ void __launch_bounds__(256) cvtgate_kernel(
    const float* __restrict__ x, const float* __restrict__ gw,
    const float* __restrict__ w1, const float* __restrict__ w2,
    const float* __restrict__ w3, const float* __restrict__ sw1,
    const float* __restrict__ sw2, const float* __restrict__ sw3,
    us* __restrict__ xb, us* __restrict__ w1b, us* __restrict__ w2b,
    us* __restrict__ w3b, us* __restrict__ sw1b, us* __restrict__ sw2b,
    us* __restrict__ sw3b, int* __restrict__ tki, float* __restrict__ tkw,
    float* __restrict__ probs) {
  if (blockIdx.x < GATE_BLKS) {
    // ---- gate: 4 tokens/block, 1 wave each, no atomics ----
    const int wv = threadIdx.x >> 6, lane = threadIdx.x & 63;
    const int s = blockIdx.x * 4 + wv;
    const float4* xs4 = (const float4*)(x + (size_t)s * CDIM);
    float acc[8] = {0, 0, 0, 0, 0, 0, 0, 0};
#pragma unroll
    for (int j = 0; j < 4; j++) {
      float4 v = xs4[lane * 4 + j];
      int c = lane * 16 + j * 4;
      us4 ov;
      ov.x = f2bf(v.x); ov.y = f2bf(v.y); ov.z = f2bf(v.z); ov.w = f2bf(v.w);
      *(us4*)(xb + (size_t)s * CDIM + c) = ov;
#pragma unroll
      for (int ee = 0; ee < 8; ee++) {
        const float* g = gw + ee * CDIM + c;
        acc[ee] += v.x * g[0] + v.y * g[1] + v.z * g[2] + v.w * g[3];
      }
    }
#pragma unroll
    for (int ee = 0; ee < 8; ee++) {
#pragma unroll
      for (int off = 32; off > 0; off >>= 1) acc[ee] += __shfl_xor(acc[ee], off, 64);
    }
    if (lane == 0) {
      float mx = acc[0];
      for (int ee = 1; ee < 8; ee++) mx = fmaxf(mx, acc[ee]);
      float p[8], sm = 0.f;
      for (int ee = 0; ee < 8; ee++) { p[ee] = expf(acc[ee] - mx); sm += p[ee]; }
      float inv = 1.f / sm;
      for (int ee = 0; ee < 8; ee++) probs[s * 8 + ee] = p[ee] * inv;
      int i0 = 0; float b0 = p[0];
      for (int ee = 1; ee < 8; ee++) if (p[ee] > b0) { b0 = p[ee]; i0 = ee; }
      int i1 = -1; float b1 = -1.f;
      for (int ee = 0; ee < 8; ee++) if (ee != i0 && p[ee] > b1) { b1 = p[ee]; i1 = ee; }
      float rw0 = b0 * inv, rw1 = b1 * inv;
      float den = 1.f / (rw0 + rw1);
      tki[2 * s] = i0; tki[2 * s + 1] = i1;
      tkw[2 * s] = rw0 * den; tkw[2 * s + 1] = rw1 * den;
    }
  } else {
    // ---- weight convert: grid-stride over remaining blocks ----
    for (int i = (blockIdx.x - GATE_BLKS) * 256 + threadIdx.x; i < R_SW3;
         i += CVT_BLKS * 256) {
      if (i < R_W1)       cvt4_rowpad(w1,  w1b,  i);
      else if (i < R_W2)  cvt4_rowpad(w2,  w2b,  i - R_W1);
      else if (i < R_W3)  cvt4_colpad(w3,  w3b,  i - R_W2);
      else if (i < R_SW1) cvt4_rowpad(sw1, sw1b, i - R_W3);
      else if (i < R_SW2) cvt4_rowpad(sw2, sw2b, i - R_SW1);
      else                cvt4_colpad(sw3, sw3b, i - R_SW2);
    }
  }
}

// ---------------- counting + routing lists + inverse map + aux loss ----------------
__global__ void __launch_bounds__(512) build_kernel(const int* __restrict__ tki,
                                                    const float* __restrict__ tkw,
                                                    const float* __restrict__ probs,
                                                    int* __restrict__ meta,
                                                    int* __restrict__ pairtok,
                                                    float* __restrict__ pairw,
                                                    int* __restrict__ invmap,
                                                    int* __restrict__ tile_expert,
                                                    float* __restrict__ aux_out) {
  const int tid = threadIdx.x, lane = tid & 63, wv = tid >> 6;
  __shared__ int s_cnt[EXP];
  __shared__ int s_amc[EXP];
  __shared__ float s_imp[EXP];
  {
    const int e = wv;
    int c_cnt = 0, c_amc = 0;
    float imp = 0.f;
    for (int s0 = 0; s0 < S_TOK; s0 += 64) {
      int s = s0 + lane;
      int i0 = tki[2 * s], i1 = tki[2 * s + 1];
      c_cnt += (i0 == e) || (i1 == e);
      c_amc += (i0 == e);
      imp += probs[s * 8 + e];
    }
#pragma unroll
    for (int off = 32; off > 0; off >>= 1) {
      c_cnt += __shfl_xor(c_cnt, off, 64);
      c_amc += __shfl_xor(c_amc, off, 64);
      imp   += __shfl_xor(imp, off, 64);
    }
    if (lane == 0) { s_cnt[e] = c_cnt; s_amc[e] = c_amc; s_imp[e] = imp; }
  }
  __syncthreads();
  int pad[EXP], start[EXP];
  int o = S_TOK;
#pragma unroll
  for (int j = 0; j < EXP; j++) {
    pad[j] = ((s_cnt[j] + 127) >> 7) << 7;
    start[j] = o;
    o += pad[j];
  }
  const int total = o;
  for (int r = tid; r < S_TOK; r += 512) { pairtok[r] = r; pairw[r] = 1.f; }
  {
    const int e = wv;
    int base = start[e];
    for (int s0 = 0; s0 < S_TOK; s0 += 64) {
      int s = s0 + lane;
      int i0 = tki[2 * s], i1 = tki[2 * s + 1];
      bool m0 = (i0 == e), m1 = (i1 == e);
      bool mm = m0 || m1;
      unsigned long long mk = __ballot(mm);
      if (mm) {
        int pos = base + __popcll(mk & ((1ull << lane) - 1ull));
        pairtok[pos] = s;
        pairw[pos] = m0 ? tkw[2 * s] : tkw[2 * s + 1];
        invmap[2 * s + (m0 ? 0 : 1)] = pos;
      }
      base += __popcll(mk);
    }
    for (int r = base + lane; r < start[e] + pad[e]; r += 64) {
      pairtok[r] = -1; pairw[r] = 0.f;
    }
  }
  if (tid < 128) {
    int ex = 8;
    if (tid >= 32) {
      int rr = tid * 128;
#pragma unroll
      for (int j = 0; j < EXP; j++)
        if (rr >= start[j] && rr < start[j] + pad[j]) ex = j;
    }
    tile_expert[tid] = ex;
  }
  if (tid == 0) {
    meta[0] = total >> 7;
    float a = 0.f;
    for (int j = 0; j < EXP; j++)
      a += (s_imp[j] * (1.f / 4096.f)) * ((float)s_amc[j] * (1.f / 4096.f));
    aux_out[0] = 8.f * a;
  }
}

// ---------------- GEMM1: h = silu(x@w1^T) * (x@w2^T) (round-6 structure) -------
__global__ void __launch_bounds__(256, 2) gemm1_kernel(
    const us* __restrict__ xb, const us* __restrict__ w1b, const us* __restrict__ w2b,
    const us* __restrict__ sw1b, const us* __restrict__ sw2b,
    const int* __restrict__ pairtok, const int* __restrict__ tile_expert,
    const int* __restrict__ meta, us* __restrict__ h) {
  const int wgid = xcd_swz(blockIdx.x, MAXTILES * NSLICE1);
  const int mt = wgid % MAXTILES;
  if (mt >= meta[0]) return;
  const int n0 = (wgid / MAXTILES) * 128;
  const int e = tile_expert[mt];
  const us* B1 = (e == 8) ? sw1b : (w1b + (size_t)e * HPAD * CDIM);
  const us* B2 = (e == 8) ? sw2b : (w2b + (size_t)e * HPAD * CDIM);
  const int row0 = mt * 128;
  __shared__ __align__(16) us sA[128 * 32];
  __shared__ __align__(16) us sB1[128 * 32];
  __shared__ __align__(16) us sB2[128 * 32];
  const int tid = threadIdx.x, lane = tid & 63;
  const int wm = tid >> 7, wn = (tid >> 6) & 1;
  const int sub = tid & 3, ra = tid >> 2;
  const int subx = sub ^ ((ra >> 1) & 3);     // inverse-swizzled global source chunk
  int t0 = pairtok[row0 + ra];      if (t0 < 0) t0 = 0;
  int t1 = pairtok[row0 + 64 + ra]; if (t1 < 0) t1 = 0;
  const us* gA0 = xb + (size_t)t0 * CDIM + subx * 8;
  const us* gA1 = xb + (size_t)t1 * CDIM + subx * 8;
  const us* gB1a = B1 + (size_t)(n0 + ra) * CDIM + subx * 8;
  const us* gB1b = B1 + (size_t)(n0 + 64 + ra) * CDIM + subx * 8;
  const us* gB2a = B2 + (size_t)(n0 + ra) * CDIM + subx * 8;
  const us* gB2b = B2 + (size_t)(n0 + 64 + ra) * CDIM + subx * 8;
  f32x4 au[4][4], av[4][4];
#pragma unroll
  for (int m = 0; m < 4; m++)
#pragma unroll
    for (int n = 0; n < 4; n++)
#pragma unroll
      for (int r = 0; r < 4; r++) { au[m][n][r] = 0.f; av[m][n][r] = 0.f; }

  const int rl = lane & 15;
  const int kx = (((lane >> 4) ^ ((lane >> 1) & 3)) << 3);  // swizzled read slot
  for (int k0 = 0; k0 < CDIM; k0 += 32) {
    gl16(gA0 + k0,  &sA[tid * 8]);
    gl16(gA1 + k0,  &sA[(tid + 256) * 8]);
    gl16(gB1a + k0, &sB1[tid * 8]);
    gl16(gB1b + k0, &sB1[(tid + 256) * 8]);
    gl16(gB2a + k0, &sB2[tid * 8]);
    gl16(gB2b + k0, &sB2[(tid + 256) * 8]);
    __syncthreads();
    bf16x8 a[4], b1[4], b2[4];
#pragma unroll
    for (int m = 0; m < 4; m++)
      a[m] = *(const bf16x8*)&sA[(wm * 64 + m * 16 + rl) * 32 + kx];
#pragma unroll
    for (int n = 0; n < 4; n++) {
      b1[n] = *(const bf16x8*)&sB1[(wn * 64 + n * 16 + rl) * 32 + kx];
      b2[n] = *(const bf16x8*)&sB2[(wn * 64 + n * 16 + rl) * 32 + kx];
    }
#pragma unroll
    for (int m = 0; m < 4; m++)
#pragma unroll
      for (int n = 0; n < 4; n++) {
        au[m][n] = __builtin_amdgcn_mfma_f32_16x16x32_bf16(a[m], b1[n], au[m][n], 0, 0, 0);
        av[m][n] = __builtin_amdgcn_mfma_f32_16x16x32_bf16(a[m], b2[n], av[m][n], 0, 0, 0);
      }
    __syncthreads();
  }
  const int rb = (lane >> 4) * 4, cb = lane & 15;
#pragma unroll
  for (int m = 0; m < 4; m++)
#pragma unroll
    for (int n = 0; n < 4; n++)
#pragma unroll
      for (int r = 0; r < 4; r++) {
        int row = row0 + wm * 64 + m * 16 + rb + r;
        int col = n0 + wn * 64 + n * 16 + cb;
        float u = au[m][n][r], v = av[m][n][r];
        float sg = 1.f / (1.f + __expf(-u));
        h[(size_t)row * HPAD + col] = f2bf(u * sg * v);
      }
}

// ---------------- GEMM2: eo = h @ w3^T, block 128x256, wave tile 64x128 -------
// Wave tile 64x128 (acc[4][8] = 128 VGPR) -> 42.7 FLOP/LDS-byte (was 32).
__global__ void __launch_bounds__(256, 2) gemm2_kernel(
    const us* __restrict__ h, const us* __restrict__ w3b, const us* __restrict__ sw3b,
    const int* __restrict__ tile_expert, const int* __restrict__ meta,
    float* __restrict__ eo) {
  const int wgid = xcd_swz(blockIdx.x, MAXTILES * NSLICE2);
  const int mt = wgid % MAXTILES;
  if (mt >= meta[0]) return;
  const int n0 = (wgid / MAXTILES) * 256;
  const int e = tile_expert[mt];
  const us* B = (e == 8) ? sw3b : (w3b + (size_t)e * CDIM * HPAD);
  const int row0 = mt * 128;
  __shared__ __align__(16) us sA[128 * 32];
  __shared__ __align__(16) us sB[256 * 32];
  const int tid = threadIdx.x, lane = tid & 63;
  const int wm = tid >> 7, wn = (tid >> 6) & 1;
  const int sub = tid & 3, ra = tid >> 2;
  const int subx = sub ^ ((ra >> 1) & 3);
  const us* gA0 = h + (size_t)(row0 + ra) * HPAD + subx * 8;
  const us* gA1 = h + (size_t)(row0 + 64 + ra) * HPAD + subx * 8;
  const us* gB0 = B + (size_t)(n0 + ra) * HPAD + subx * 8;
  const us* gB1 = B + (size_t)(n0 + 64 + ra) * HPAD + subx * 8;
  const us* gB2 = B + (size_t)(n0 + 128 + ra) * HPAD + subx * 8;
  const us* gB3 = B + (size_t)(n0 + 192 + ra) * HPAD + subx * 8;
  f32x4 ac[4][8];
#pragma unroll
  for (int m = 0; m < 4; m++)
#pragma unroll
    for (int n = 0; n < 8; n++)
#pragma unroll
      for (int r = 0; r < 4; r++) ac[m][n][r] = 0.f;

  const int rl = lane & 15;
  const int kx = (((lane >> 4) ^ ((lane >> 1) & 3)) << 3);
  for (int k0 = 0; k0 < HPAD; k0 += 32) {
    gl16(gA0 + k0, &sA[tid * 8]);
    gl16(gA1 + k0, &sA[(tid + 256) * 8]);
    gl16(gB0 + k0, &sB[tid * 8]);
    gl16(gB1 + k0, &sB[(tid + 256) * 8]);
    gl16(gB2 + k0, &sB[(tid + 512) * 8]);
    gl16(gB3 + k0, &sB[(tid + 768) * 8]);
    __syncthreads();
    bf16x8 a[4], b[8];
#pragma unroll
    for (int m = 0; m < 4; m++)
      a[m] = *(const bf16x8*)&sA[(wm * 64 + m * 16 + rl) * 32 + kx];
#pragma unroll
    for (int n = 0; n < 8; n++)
      b[n] = *(const bf16x8*)&sB[(wn * 128 + n * 16 + rl) * 32 + kx];
#pragma unroll
    for (int m = 0; m < 4; m++)
#pragma unroll
      for (int n = 0; n < 8; n++)
        ac[m][n] = __builtin_amdgcn_mfma_f32_16x16x32_bf16(a[m], b[n], ac[m][n], 0, 0, 0);
    __syncthreads();
  }
  const int rb = (lane >> 4) * 4, cb = lane & 15;
#pragma unroll
  for (int m = 0; m < 4; m++)
#pragma unroll
    for (int n = 0; n < 8; n++)
#pragma unroll
      for (int r = 0; r < 4; r++) {
        int row = row0 + wm * 64 + m * 16 + rb + r;
        int col = n0 + wn * 128 + n * 16 + cb;
        eo[(size_t)row * CDIM + col] = ac[m][n][r];
      }
}

// ---------------- combine ----------------
__global__ void __launch_bounds__(256) combine_kernel(const float* __restrict__ eo,
                                                      const int* __restrict__ invmap,
                                                      const float* __restrict__ pairw,
                                                      float* __restrict__ out) {
  const int s = blockIdx.x;
  const int c = threadIdx.x * 4;
  const int j0 = invmap[2 * s], j1 = invmap[2 * s + 1];
  const float w0 = pairw[j0], w1 = pairw[j1];
  float4 a = *(const float4*)(eo + (size_t)s * CDIM + c);
  float4 b = *(const float4*)(eo + (size_t)j0 * CDIM + c);
  float4 d = *(const float4*)(eo + (size_t)j1 * CDIM + c);
  float4 o;
  o.x = a.x + w0 * b.x + w1 * d.x;
  o.y = a.y + w0 * b.y + w1 * d.y;
  o.z = a.z + w0 * b.z + w1 * d.z;
  o.w = a.w + w0 * b.w + w1 * d.w;
  *(float4*)(out + (size_t)s * CDIM + c) = o;
}

extern "C" void kernel_launch(void* const* d_in, const int* in_sizes, int n_in,
                              void* d_out, int out_size, void* d_ws, size_t ws_size,
                              hipStream_t stream) {
  const float* x   = (const float*)d_in[0];
  const float* gw  = (const float*)d_in[1];
  const float* w1  = (const float*)d_in[2];
  const float* w2  = (const float*)d_in[3];
  const float* w3  = (const float*)d_in[4];
  const float* sw1 = (const float*)d_in[5];
  const float* sw2 = (const float*)d_in[6];
  const float* sw3 = (const float*)d_in[7];
  float* out = (float*)d_out;
  char* ws = (char*)d_ws;
  size_t off = 0;
  auto take = [&](size_t bytes) -> char* {
    char* p = ws + off;
    off = (off + bytes + 255) & ~(size_t)255;
    return p;
  };
  us* xb    = (us*)take((size_t)S_TOK * CDIM * 2);
  us* w1b   = (us*)take((size_t)EXP * HPAD * CDIM * 2);
  us* w2b   = (us*)take((size_t)EXP * HPAD * CDIM * 2);
  us* w3b   = (us*)take((size_t)EXP * CDIM * HPAD * 2);
  us* sw1b  = (us*)take((size_t)HPAD * CDIM * 2);
  us* sw2b  = (us*)take((size_t)HPAD * CDIM * 2);
  us* sw3b  = (us*)take((size_t)CDIM * HPAD * 2);
  us* hbuf  = (us*)take((size_t)MAXROWS * HPAD * 2);
  int* pairtok = (int*)take(MAXROWS * 4);
  float* pairw = (float*)take(MAXROWS * 4);
  int* invmap  = (int*)take(S_TOK * 2 * 4);
  int* tile_expert = (int*)take(128 * 4);
  int* tki = (int*)take(S_TOK * 2 * 4);
  float* tkw = (float*)take(S_TOK * 2 * 4);
  float* probs = (float*)take(S_TOK * EXP * 4);
  int* meta = (int*)take(256);
  float* eo = (float*)w1b;  // aliases w1b+w2b, dead after gemm1
  if (off > ws_size) {
    fprintf(stderr, "MoE kernel: ws too small, need %zu got %zu\n", off, ws_size);
    return;
  }
  cvtgate_kernel<<<GATE_BLKS + CVT_BLKS, 256, 0, stream>>>(
      x, gw, w1, w2, w3, sw1, sw2, sw3,
      xb, w1b, w2b, w3b, sw1b, sw2b, sw3b, tki, tkw, probs);
  build_kernel<<<1, 512, 0, stream>>>(tki, tkw, probs, meta, pairtok, pairw, invmap,
                                      tile_expert, out + (size_t)S_TOK * CDIM);
  gemm1_kernel<<<MAXTILES * NSLICE1, 256, 0, stream>>>(
      xb, w1b, w2b, sw1b, sw2b, pairtok, tile_expert, meta, hbuf);
  gemm2_kernel<<<MAXTILES * NSLICE2, 256, 0, stream>>>(
      hbuf, w3b, sw3b, tile_expert, meta, eo);
  combine_kernel<<<S_TOK, 256, 0, stream>>>(eo, invmap, pairw, out);
}

// Round 9
// 429.383 us; speedup vs baseline: 1.2131x; 1.0993x over previous
//
#include <hip/hip_runtime.h>
#include <cstdio>
#include <cstdint>

#define S_TOK 4096
#define CDIM  1024
#define EXP   8
#define HRAW  2744
#define HPAD  2816
#define MAXROWS  13312   // 104 tiles * 128
#define MAXTILES 104
#define NSLICE1  (HPAD / 128)   // 22
#define NSLICE2  (CDIM / 256)   // 4  (gemm2 block = 128x256)
#define G1_BLKS  (MAXTILES * NSLICE1)  // 2288 (divisible by 8)

typedef __attribute__((ext_vector_type(8))) short bf16x8;
typedef __attribute__((ext_vector_type(4))) float f32x4;
typedef __attribute__((ext_vector_type(4))) unsigned short us4;
typedef unsigned short us;

__device__ __forceinline__ us f2bf(float f) {
  unsigned u = __float_as_uint(f);
  u += 0x7fffu + ((u >> 16) & 1u);
  return (us)(u >> 16);
}

__device__ __forceinline__ void gl16(const us* g, us* l) {
  __builtin_amdgcn_global_load_lds((__attribute__((address_space(1))) void*)g,
                                   (__attribute__((address_space(3))) void*)l,
                                   16, 0, 0);
}

// bijective XCD swizzle (m204)
__device__ __forceinline__ int xcd_swz(int orig, int nwg) {
  int q = nwg >> 3, r = nwg & 7;
  int x = orig & 7, idx = orig >> 3;
  return (x < r ? x * (q + 1) : r * (q + 1) + (x - r) * q) + idx;
}

// ---------------- conversion helpers (fp32 -> bf16, padded) ----------------
#define CH_RP1  (HPAD * CDIM / 4)          // chunks per rowpad matrix
#define CH_CPR  (HPAD / 4)                 // chunks per colpad row

__device__ __forceinline__ void cvt4_rowpad(const float* __restrict__ src,
                                            us* __restrict__ dst, int idx) {
  int m = idx / CH_RP1, rem = idx - m * CH_RP1;
  int r = rem >> 8, c4 = rem & 255;
  us4 o;
  if (r < HRAW) {
    float4 v = *(const float4*)(src + ((size_t)(m * HRAW + r) * CDIM + c4 * 4));
    o.x = f2bf(v.x); o.y = f2bf(v.y); o.z = f2bf(v.z); o.w = f2bf(v.w);
  } else { o.x = 0; o.y = 0; o.z = 0; o.w = 0; }
  *(us4*)(dst + ((size_t)(m * HPAD + r) * CDIM + c4 * 4)) = o;
}

__device__ __forceinline__ void cvt4_colpad(const float* __restrict__ src,
                                            us* __restrict__ dst, int idx) {
  int r = idx / CH_CPR, c4 = idx - r * CH_CPR;
  int c = c4 * 4;
  us4 o;
  if (c < HRAW) {
    float4 v = *(const float4*)(src + (size_t)r * HRAW + c);
    o.x = f2bf(v.x); o.y = f2bf(v.y); o.z = f2bf(v.z); o.w = f2bf(v.w);
  } else { o.x = 0; o.y = 0; o.z = 0; o.w = 0; }
  *(us4*)(dst + (size_t)r * HPAD + c) = o;
}

// ---------------- gating (standalone, first) ----------------
__global__ void __launch_bounds__(256) gate_kernel(const float* __restrict__ x,
                                                   const float* __restrict__ gw,
                                                   us* __restrict__ xb,
                                                   int* __restrict__ tki,
                                                   float* __restrict__ tkw,
                                                   float* __restrict__ probs) {
  const int wv = threadIdx.x >> 6, lane = threadIdx.x & 63;
  const int s = blockIdx.x * 4 + wv;
  const float4* xs4 = (const float4*)(x + (size_t)s * CDIM);
  float acc[8] = {0, 0, 0, 0, 0, 0, 0, 0};
#pragma unroll
  for (int j = 0; j < 4; j++) {
    float4 v = xs4[lane * 4 + j];
    int c = lane * 16 + j * 4;
    us4 ov;
    ov.x = f2bf(v.x); ov.y = f2bf(v.y); ov.z = f2bf(v.z); ov.w = f2bf(v.w);
    *(us4*)(xb + (size_t)s * CDIM + c) = ov;
#pragma unroll
    for (int ee = 0; ee < 8; ee++) {
      const float* g = gw + ee * CDIM + c;
      acc[ee] += v.x * g[0] + v.y * g[1] + v.z * g[2] + v.w * g[3];
    }
  }
#pragma unroll
  for (int ee = 0; ee < 8; ee++) {
#pragma unroll
    for (int off = 32; off > 0; off >>= 1) acc[ee] += __shfl_xor(acc[ee], off, 64);
  }
  if (lane == 0) {
    float mx = acc[0];
    for (int ee = 1; ee < 8; ee++) mx = fmaxf(mx, acc[ee]);
    float p[8], sm = 0.f;
    for (int ee = 0; ee < 8; ee++) { p[ee] = expf(acc[ee] - mx); sm += p[ee]; }
    float inv = 1.f / sm;
    for (int ee = 0; ee < 8; ee++) probs[s * 8 + ee] = p[ee] * inv;
    int i0 = 0; float b0 = p[0];
    for (int ee = 1; ee < 8; ee++) if (p[ee] > b0) { b0 = p[ee]; i0 = ee; }
    int i1 = -1; float b1 = -1.f;
    for (int ee = 0; ee < 8; ee++) if (ee != i0 && p[ee] > b1) { b1 = p[ee]; i1 = ee; }
    float rw0 = b0 * inv, rw1 = b1 * inv;
    float den = 1.f / (rw0 + rw1);
    tki[2 * s] = i0; tki[2 * s + 1] = i1;
    tkw[2 * s] = rw0 * den; tkw[2 * s + 1] = rw1 * den;
  }
}

// ---------------- cvt(w1,w2,sw1,sw2) with build fused as block 0 ----------------
#define CVTAB_BLKS 2048
#define AB_W1   (8 * CH_RP1)
#define AB_W2   (AB_W1 + 8 * CH_RP1)
#define AB_SW1  (AB_W2 + CH_RP1)
#define AB_SW2  (AB_SW1 + CH_RP1)

__global__ void __launch_bounds__(512) cvtab_build_kernel(
    const float* __restrict__ w1, const float* __restrict__ w2,
    const float* __restrict__ sw1, const float* __restrict__ sw2,
    us* __restrict__ w1b, us* __restrict__ w2b,
    us* __restrict__ sw1b, us* __restrict__ sw2b,
    const int* __restrict__ tki, const float* __restrict__ tkw,
    const float* __restrict__ probs, int* __restrict__ meta,
    int* __restrict__ pairtok, float* __restrict__ pairw,
    int* __restrict__ invmap, int* __restrict__ tile_expert,
    float* __restrict__ aux_out) {
  if (blockIdx.x == 0) {
    // ---- build (depends only on gate_kernel, prior launch) ----
    const int tid = threadIdx.x, lane = tid & 63, wv = tid >> 6;
    __shared__ int s_cnt[EXP];
    __shared__ int s_amc[EXP];
    __shared__ float s_imp[EXP];
    {
      const int e = wv;
      int c_cnt = 0, c_amc = 0;
      float imp = 0.f;
      for (int s0 = 0; s0 < S_TOK; s0 += 64) {
        int s = s0 + lane;
        int i0 = tki[2 * s], i1 = tki[2 * s + 1];
        c_cnt += (i0 == e) || (i1 == e);
        c_amc += (i0 == e);
        imp += probs[s * 8 + e];
      }
#pragma unroll
      for (int off = 32; off > 0; off >>= 1) {
        c_cnt += __shfl_xor(c_cnt, off, 64);
        c_amc += __shfl_xor(c_amc, off, 64);
        imp   += __shfl_xor(imp, off, 64);
      }
      if (lane == 0) { s_cnt[e] = c_cnt; s_amc[e] = c_amc; s_imp[e] = imp; }
    }
    __syncthreads();
    int pad[EXP], start[EXP];
    int o = S_TOK;
#pragma unroll
    for (int j = 0; j < EXP; j++) {
      pad[j] = ((s_cnt[j] + 127) >> 7) << 7;
      start[j] = o;
      o += pad[j];
    }
    const int total = o;
    for (int r = tid; r < S_TOK; r += 512) { pairtok[r] = r; pairw[r] = 1.f; }
    {
      const int e = wv;
      int base = start[e];
      for (int s0 = 0; s0 < S_TOK; s0 += 64) {
        int s = s0 + lane;
        int i0 = tki[2 * s], i1 = tki[2 * s + 1];
        bool m0 = (i0 == e), m1 = (i1 == e);
        bool mm = m0 || m1;
        unsigned long long mk = __ballot(mm);
        if (mm) {
          int pos = base + __popcll(mk & ((1ull << lane) - 1ull));
          pairtok[pos] = s;
          pairw[pos] = m0 ? tkw[2 * s] : tkw[2 * s + 1];
          invmap[2 * s + (m0 ? 0 : 1)] = pos;
        }
        base += __popcll(mk);
      }
      for (int r = base + lane; r < start[e] + pad[e]; r += 64) {
        pairtok[r] = -1; pairw[r] = 0.f;
      }
    }
    if (tid < 128) {
      int ex = 8;
      if (tid >= 32) {
        int rr = tid * 128;
#pragma unroll
        for (int j = 0; j < EXP; j++)
          if (rr >= start[j] && rr < start[j] + pad[j]) ex = j;
      }
      tile_expert[tid] = ex;
    }
    if (tid == 0) {
      meta[0] = total >> 7;
      float a = 0.f;
      for (int j = 0; j < EXP; j++)
        a += (s_imp[j] * (1.f / 4096.f)) * ((float)s_amc[j] * (1.f / 4096.f));
      aux_out[0] = 8.f * a;
    }
    return;
  }
  // ---- cvt of w1, w2, sw1, sw2 ----
  for (int i = (blockIdx.x - 1) * 512 + threadIdx.x; i < AB_SW2;
       i += (CVTAB_BLKS - 1) * 512) {
    if (i < AB_W1)       cvt4_rowpad(w1,  w1b,  i);
    else if (i < AB_W2)  cvt4_rowpad(w2,  w2b,  i - AB_W1);
    else if (i < AB_SW1) cvt4_rowpad(sw1, sw1b, i - AB_W2);
    else                 cvt4_rowpad(sw2, sw2b, i - AB_SW1);
  }
}

// ---------------- GEMM1 (round-6 structure) + w3/sw3 cvt tail blocks ----------
#define W3CVT_BLKS 1024
#define W3_CHUNKS  (8 * CDIM * CH_CPR)
#define W3TOT      (W3_CHUNKS + CDIM * CH_CPR)

__global__ void __launch_bounds__(256, 2) gemm1_kernel(
    const us* __restrict__ xb, const us* __restrict__ w1b, const us* __restrict__ w2b,
    const us* __restrict__ sw1b, const us* __restrict__ sw2b,
    const int* __restrict__ pairtok, const int* __restrict__ tile_expert,
    const int* __restrict__ meta, us* __restrict__ h,
    const float* __restrict__ w3, const float* __restrict__ sw3,
    us* __restrict__ w3b, us* __restrict__ sw3b) {
  if (blockIdx.x >= G1_BLKS) {
    // ---- hidden co-tenant: w3/sw3 conversion (needed only by gemm2) ----
    for (int i = (blockIdx.x - G1_BLKS) * 256 + threadIdx.x; i < W3TOT;
         i += W3CVT_BLKS * 256) {
      if (i < W3_CHUNKS) cvt4_colpad(w3,  w3b,  i);
      else               cvt4_colpad(sw3, sw3b, i - W3_CHUNKS);
    }
    return;
  }
  const int wgid = xcd_swz(blockIdx.x, G1_BLKS);
  const int mt = wgid % MAXTILES;
  if (mt >= meta[0]) return;
  const int n0 = (wgid / MAXTILES) * 128;
  const int e = tile_expert[mt];
  const us* B1 = (e == 8) ? sw1b : (w1b + (size_t)e * HPAD * CDIM);
  const us* B2 = (e == 8) ? sw2b : (w2b + (size_t)e * HPAD * CDIM);
  const int row0 = mt * 128;
  __shared__ __align__(16) us sA[128 * 32];
  __shared__ __align__(16) us sB1[128 * 32];
  __shared__ __align__(16) us sB2[128 * 32];
  const int tid = threadIdx.x, lane = tid & 63;
  const int wm = tid >> 7, wn = (tid >> 6) & 1;
  const int sub = tid & 3, ra = tid >> 2;
  const int subx = sub ^ ((ra >> 1) & 3);     // inverse-swizzled global source chunk
  int t0 = pairtok[row0 + ra];      if (t0 < 0) t0 = 0;
  int t1 = pairtok[row0 + 64 + ra]; if (t1 < 0) t1 = 0;
  const us* gA0 = xb + (size_t)t0 * CDIM + subx * 8;
  const us* gA1 = xb + (size_t)t1 * CDIM + subx * 8;
  const us* gB1a = B1 + (size_t)(n0 + ra) * CDIM + subx * 8;
  const us* gB1b = B1 + (size_t)(n0 + 64 + ra) * CDIM + subx * 8;
  const us* gB2a = B2 + (size_t)(n0 + ra) * CDIM + subx * 8;
  const us* gB2b = B2 + (size_t)(n0 + 64 + ra) * CDIM + subx * 8;
  f32x4 au[4][4], av[4][4];
#pragma unroll
  for (int m = 0; m < 4; m++)
#pragma unroll
    for (int n = 0; n < 4; n++)
#pragma unroll
      for (int r = 0; r < 4; r++) { au[m][n][r] = 0.f; av[m][n][r] = 0.f; }

  const int rl = lane & 15;
  const int kx = (((lane >> 4) ^ ((lane >> 1) & 3)) << 3);  // swizzled read slot
  for (int k0 = 0; k0 < CDIM; k0 += 32) {
    gl16(gA0 + k0,  &sA[tid * 8]);
    gl16(gA1 + k0,  &sA[(tid + 256) * 8]);
    gl16(gB1a + k0, &sB1[tid * 8]);
    gl16(gB1b + k0, &sB1[(tid + 256) * 8]);
    gl16(gB2a + k0, &sB2[tid * 8]);
    gl16(gB2b + k0, &sB2[(tid + 256) * 8]);
    __syncthreads();
    bf16x8 a[4], b1[4], b2[4];
#pragma unroll
    for (int m = 0; m < 4; m++)
      a[m] = *(const bf16x8*)&sA[(wm * 64 + m * 16 + rl) * 32 + kx];
#pragma unroll
    for (int n = 0; n < 4; n++) {
      b1[n] = *(const bf16x8*)&sB1[(wn * 64 + n * 16 + rl) * 32 + kx];
      b2[n] = *(const bf16x8*)&sB2[(wn * 64 + n * 16 + rl) * 32 + kx];
    }
#pragma unroll
    for (int m = 0; m < 4; m++)
#pragma unroll
      for (int n = 0; n < 4; n++) {
        au[m][n] = __builtin_amdgcn_mfma_f32_16x16x32_bf16(a[m], b1[n], au[m][n], 0, 0, 0);
        av[m][n] = __builtin_amdgcn_mfma_f32_16x16x32_bf16(a[m], b2[n], av[m][n], 0, 0, 0);
      }
    __syncthreads();
  }
  const int rb = (lane >> 4) * 4, cb = lane & 15;
#pragma unroll
  for (int m = 0; m < 4; m++)
#pragma unroll
    for (int n = 0; n < 4; n++)
#pragma unroll
      for (int r = 0; r < 4; r++) {
        int row = row0 + wm * 64 + m * 16 + rb + r;
        int col = n0 + wn * 64 + n * 16 + cb;
        float u = au[m][n][r], v = av[m][n][r];
        float sg = 1.f / (1.f + __expf(-u));
        h[(size_t)row * HPAD + col] = f2bf(u * sg * v);
      }
}

// ---------------- GEMM2: eo = h @ w3^T, block 128x256, wave tile 64x128 -------
__global__ void __launch_bounds__(256, 2) gemm2_kernel(
    const us* __restrict__ h, const us* __restrict__ w3b, const us* __restrict__ sw3b,
    const int* __restrict__ tile_expert, const int* __restrict__ meta,
    float* __restrict__ eo) {
  const int wgid = xcd_swz(blockIdx.x, MAXTILES * NSLICE2);
  const int mt = wgid % MAXTILES;
  if (mt >= meta[0]) return;
  const int n0 = (wgid / MAXTILES) * 256;
  const int e = tile_expert[mt];
  const us* B = (e == 8) ? sw3b : (w3b + (size_t)e * CDIM * HPAD);
  const int row0 = mt * 128;
  __shared__ __align__(16) us sA[128 * 32];
  __shared__ __align__(16) us sB[256 * 32];
  const int tid = threadIdx.x, lane = tid & 63;
  const int wm = tid >> 7, wn = (tid >> 6) & 1;
  const int sub = tid & 3, ra = tid >> 2;
  const int subx = sub ^ ((ra >> 1) & 3);
  const us* gA0 = h + (size_t)(row0 + ra) * HPAD + subx * 8;
  const us* gA1 = h + (size_t)(row0 + 64 + ra) * HPAD + subx * 8;
  const us* gB0 = B + (size_t)(n0 + ra) * HPAD + subx * 8;
  const us* gB1 = B + (size_t)(n0 + 64 + ra) * HPAD + subx * 8;
  const us* gB2 = B + (size_t)(n0 + 128 + ra) * HPAD + subx * 8;
  const us* gB3 = B + (size_t)(n0 + 192 + ra) * HPAD + subx * 8;
  f32x4 ac[4][8];
#pragma unroll
  for (int m = 0; m < 4; m++)
#pragma unroll
    for (int n = 0; n < 8; n++)
#pragma unroll
      for (int r = 0; r < 4; r++) ac[m][n][r] = 0.f;

  const int rl = lane & 15;
  const int kx = (((lane >> 4) ^ ((lane >> 1) & 3)) << 3);
  for (int k0 = 0; k0 < HPAD; k0 += 32) {
    gl16(gA0 + k0, &sA[tid * 8]);
    gl16(gA1 + k0, &sA[(tid + 256) * 8]);
    gl16(gB0 + k0, &sB[tid * 8]);
    gl16(gB1 + k0, &sB[(tid + 256) * 8]);
    gl16(gB2 + k0, &sB[(tid + 512) * 8]);
    gl16(gB3 + k0, &sB[(tid + 768) * 8]);
    __syncthreads();
    bf16x8 a[4], b[8];
#pragma unroll
    for (int m = 0; m < 4; m++)
      a[m] = *(const bf16x8*)&sA[(wm * 64 + m * 16 + rl) * 32 + kx];
#pragma unroll
    for (int n = 0; n < 8; n++)
      b[n] = *(const bf16x8*)&sB[(wn * 128 + n * 16 + rl) * 32 + kx];
#pragma unroll
    for (int m = 0; m < 4; m++)
#pragma unroll
      for (int n = 0; n < 8; n++)
        ac[m][n] = __builtin_amdgcn_mfma_f32_16x16x32_bf16(a[m], b[n], ac[m][n], 0, 0, 0);
    __syncthreads();
  }
  const int rb = (lane >> 4) * 4, cb = lane & 15;
#pragma unroll
  for (int m = 0; m < 4; m++)
#pragma unroll
    for (int n = 0; n < 8; n++)
#pragma unroll
      for (int r = 0; r < 4; r++) {
        int row = row0 + wm * 64 + m * 16 + rb + r;
        int col = n0 + wn * 128 + n * 16 + cb;
        eo[(size_t)row * CDIM + col] = ac[m][n][r];
      }
}

// ---------------- combine ----------------
__global__ void __launch_bounds__(256) combine_kernel(const float* __restrict__ eo,
                                                      const int* __restrict__ invmap,
                                                      const float* __restrict__ pairw,
                                                      float* __restrict__ out) {
  const int s = blockIdx.x;
  const int c = threadIdx.x * 4;
  const int j0 = invmap[2 * s], j1 = invmap[2 * s + 1];
  const float w0 = pairw[j0], w1 = pairw[j1];
  float4 a = *(const float4*)(eo + (size_t)s * CDIM + c);
  float4 b = *(const float4*)(eo + (size_t)j0 * CDIM + c);
  float4 d = *(const float4*)(eo + (size_t)j1 * CDIM + c);
  float4 o;
  o.x = a.x + w0 * b.x + w1 * d.x;
  o.y = a.y + w0 * b.y + w1 * d.y;
  o.z = a.z + w0 * b.z + w1 * d.z;
  o.w = a.w + w0 * b.w + w1 * d.w;
  *(float4*)(out + (size_t)s * CDIM + c) = o;
}

extern "C" void kernel_launch(void* const* d_in, const int* in_sizes, int n_in,
                              void* d_out, int out_size, void* d_ws, size_t ws_size,
                              hipStream_t stream) {
  const float* x   = (const float*)d_in[0];
  const float* gw  = (const float*)d_in[1];
  const float* w1  = (const float*)d_in[2];
  const float* w2  = (const float*)d_in[3];
  const float* w3  = (const float*)d_in[4];
  const float* sw1 = (const float*)d_in[5];
  const float* sw2 = (const float*)d_in[6];
  const float* sw3 = (const float*)d_in[7];
  float* out = (float*)d_out;
  char* ws = (char*)d_ws;
  size_t off = 0;
  auto take = [&](size_t bytes) -> char* {
    char* p = ws + off;
    off = (off + bytes + 255) & ~(size_t)255;
    return p;
  };
  us* xb    = (us*)take((size_t)S_TOK * CDIM * 2);
  us* w1b   = (us*)take((size_t)EXP * HPAD * CDIM * 2);
  us* w2b   = (us*)take((size_t)EXP * HPAD * CDIM * 2);
  us* w3b   = (us*)take((size_t)EXP * CDIM * HPAD * 2);
  us* sw1b  = (us*)take((size_t)HPAD * CDIM * 2);
  us* sw2b  = (us*)take((size_t)HPAD * CDIM * 2);
  us* sw3b  = (us*)take((size_t)CDIM * HPAD * 2);
  us* hbuf  = (us*)take((size_t)MAXROWS * HPAD * 2);
  int* pairtok = (int*)take(MAXROWS * 4);
  float* pairw = (float*)take(MAXROWS * 4);
  int* invmap  = (int*)take(S_TOK * 2 * 4);
  int* tile_expert = (int*)take(128 * 4);
  int* tki = (int*)take(S_TOK * 2 * 4);
  float* tkw = (float*)take(S_TOK * 2 * 4);
  float* probs = (float*)take(S_TOK * EXP * 4);
  int* meta = (int*)take(256);
  float* eo = (float*)w1b;  // aliases w1b+w2b, dead after gemm1
  if (off > ws_size) {
    fprintf(stderr, "MoE kernel: ws too small, need %zu got %zu\n", off, ws_size);
    return;
  }
  gate_kernel<<<S_TOK / 4, 256, 0, stream>>>(x, gw, xb, tki, tkw, probs);
  cvtab_build_kernel<<<CVTAB_BLKS, 512, 0, stream>>>(
      w1, w2, sw1, sw2, w1b, w2b, sw1b, sw2b,
      tki, tkw, probs, meta, pairtok, pairw, invmap, tile_expert,
      out + (size_t)S_TOK * CDIM);
  gemm1_kernel<<<G1_BLKS + W3CVT_BLKS, 256, 0, stream>>>(
      xb, w1b, w2b, sw1b, sw2b, pairtok, tile_expert, meta, hbuf,
      w3, sw3, w3b, sw3b);
  gemm2_kernel<<<MAXTILES * NSLICE2, 256, 0, stream>>>(
      hbuf, w3b, sw3b, tile_expert, meta, eo);
  combine_kernel<<<S_TOK, 256, 0, stream>>>(eo, invmap, pairw, out);
}

// Round 11
// 400.810 us; speedup vs baseline: 1.2996x; 1.0713x over previous
//
#include <hip/hip_runtime.h>
#include <cstdio>
#include <cstdint>

#define S_TOK 4096
#define CDIM  1024
#define EXP   8
#define HRAW  2744
#define HPAD  2816
#define MAXROWS  13312   // 104 tiles * 128
#define MAXTILES 104
#define NSLICE1  (HPAD / 128)   // 22
#define NSLICE2  (CDIM / 256)   // 4  (gemm2 block = 128x256)
#define G1_BLKS  (MAXTILES * NSLICE1)  // 2288 (divisible by 8)

typedef __attribute__((ext_vector_type(8))) short bf16x8;
typedef __attribute__((ext_vector_type(4))) float f32x4;
typedef __attribute__((ext_vector_type(4))) unsigned short us4;
typedef unsigned short us;

__device__ __forceinline__ us f2bf(float f) {
  unsigned u = __float_as_uint(f);
  u += 0x7fffu + ((u >> 16) & 1u);
  return (us)(u >> 16);
}
__device__ __forceinline__ float bf2f(us v) {
  return __uint_as_float((unsigned)v << 16);
}

__device__ __forceinline__ void gl16(const us* g, us* l) {
  __builtin_amdgcn_global_load_lds((__attribute__((address_space(1))) void*)g,
                                   (__attribute__((address_space(3))) void*)l,
                                   16, 0, 0);
}

// bijective XCD swizzle (m204)
__device__ __forceinline__ int xcd_swz(int orig, int nwg) {
  int q = nwg >> 3, r = nwg & 7;
  int x = orig & 7, idx = orig >> 3;
  return (x < r ? x * (q + 1) : r * (q + 1) + (x - r) * q) + idx;
}

// ---------------- conversion helpers (fp32 -> bf16, padded) ----------------
#define CH_RP1  (HPAD * CDIM / 4)          // chunks per rowpad matrix
#define CH_CPR  (HPAD / 4)                 // chunks per colpad row

__device__ __forceinline__ void cvt4_rowpad(const float* __restrict__ src,
                                            us* __restrict__ dst, int idx) {
  int m = idx / CH_RP1, rem = idx - m * CH_RP1;
  int r = rem >> 8, c4 = rem & 255;
  us4 o;
  if (r < HRAW) {
    float4 v = *(const float4*)(src + ((size_t)(m * HRAW + r) * CDIM + c4 * 4));
    o.x = f2bf(v.x); o.y = f2bf(v.y); o.z = f2bf(v.z); o.w = f2bf(v.w);
  } else { o.x = 0; o.y = 0; o.z = 0; o.w = 0; }
  *(us4*)(dst + ((size_t)(m * HPAD + r) * CDIM + c4 * 4)) = o;
}

__device__ __forceinline__ void cvt4_colpad(const float* __restrict__ src,
                                            us* __restrict__ dst, int idx) {
  int r = idx / CH_CPR, c4 = idx - r * CH_CPR;
  int c = c4 * 4;
  us4 o;
  if (c < HRAW) {
    float4 v = *(const float4*)(src + (size_t)r * HRAW + c);
    o.x = f2bf(v.x); o.y = f2bf(v.y); o.z = f2bf(v.z); o.w = f2bf(v.w);
  } else { o.x = 0; o.y = 0; o.z = 0; o.w = 0; }
  *(us4*)(dst + (size_t)r * HPAD + c) = o;
}

// ---------------- gating (standalone, first) ----------------
__global__ void __launch_bounds__(256) gate_kernel(const float* __restrict__ x,
                                                   const float* __restrict__ gw,
                                                   us* __restrict__ xb,
                                                   int* __restrict__ tki,
                                                   float* __restrict__ tkw,
                                                   float* __restrict__ probs) {
  const int wv = threadIdx.x >> 6, lane = threadIdx.x & 63;
  const int s = blockIdx.x * 4 + wv;
  const float4* xs4 = (const float4*)(x + (size_t)s * CDIM);
  float acc[8] = {0, 0, 0, 0, 0, 0, 0, 0};
#pragma unroll
  for (int j = 0; j < 4; j++) {
    float4 v = xs4[lane * 4 + j];
    int c = lane * 16 + j * 4;
    us4 ov;
    ov.x = f2bf(v.x); ov.y = f2bf(v.y); ov.z = f2bf(v.z); ov.w = f2bf(v.w);
    *(us4*)(xb + (size_t)s * CDIM + c) = ov;
#pragma unroll
    for (int ee = 0; ee < 8; ee++) {
      const float* g = gw + ee * CDIM + c;
      acc[ee] += v.x * g[0] + v.y * g[1] + v.z * g[2] + v.w * g[3];
    }
  }
#pragma unroll
  for (int ee = 0; ee < 8; ee++) {
#pragma unroll
    for (int off = 32; off > 0; off >>= 1) acc[ee] += __shfl_xor(acc[ee], off, 64);
  }
  if (lane == 0) {
    float mx = acc[0];
    for (int ee = 1; ee < 8; ee++) mx = fmaxf(mx, acc[ee]);
    float p[8], sm = 0.f;
    for (int ee = 0; ee < 8; ee++) { p[ee] = expf(acc[ee] - mx); sm += p[ee]; }
    float inv = 1.f / sm;
    for (int ee = 0; ee < 8; ee++) probs[s * 8 + ee] = p[ee] * inv;
    int i0 = 0; float b0 = p[0];
    for (int ee = 1; ee < 8; ee++) if (p[ee] > b0) { b0 = p[ee]; i0 = ee; }
    int i1 = -1; float b1 = -1.f;
    for (int ee = 0; ee < 8; ee++) if (ee != i0 && p[ee] > b1) { b1 = p[ee]; i1 = ee; }
    float rw0 = b0 * inv, rw1 = b1 * inv;
    float den = 1.f / (rw0 + rw1);
    tki[2 * s] = i0; tki[2 * s + 1] = i1;
    tkw[2 * s] = rw0 * den; tkw[2 * s + 1] = rw1 * den;
  }
}

// ---------------- cvt(w1,w2,sw1,sw2) with build fused as block 0 ----------------
#define CVTAB_BLKS 2048
#define AB_W1   (8 * CH_RP1)
#define AB_W2   (AB_W1 + 8 * CH_RP1)
#define AB_SW1  (AB_W2 + CH_RP1)
#define AB_SW2  (AB_SW1 + CH_RP1)

__global__ void __launch_bounds__(512) cvtab_build_kernel(
    const float* __restrict__ w1, const float* __restrict__ w2,
    const float* __restrict__ sw1, const float* __restrict__ sw2,
    us* __restrict__ w1b, us* __restrict__ w2b,
    us* __restrict__ sw1b, us* __restrict__ sw2b,
    const int* __restrict__ tki, const float* __restrict__ tkw,
    const float* __restrict__ probs, int* __restrict__ meta,
    int* __restrict__ pairtok, float* __restrict__ pairw,
    int* __restrict__ invmap, int* __restrict__ tile_expert,
    float* __restrict__ aux_out) {
  if (blockIdx.x == 0) {
    const int tid = threadIdx.x, lane = tid & 63, wv = tid >> 6;
    __shared__ int s_cnt[EXP];
    __shared__ int s_amc[EXP];
    __shared__ float s_imp[EXP];
    {
      const int e = wv;
      int c_cnt = 0, c_amc = 0;
      float imp = 0.f;
      for (int s0 = 0; s0 < S_TOK; s0 += 64) {
        int s = s0 + lane;
        int i0 = tki[2 * s], i1 = tki[2 * s + 1];
        c_cnt += (i0 == e) || (i1 == e);
        c_amc += (i0 == e);
        imp += probs[s * 8 + e];
      }
#pragma unroll
      for (int off = 32; off > 0; off >>= 1) {
        c_cnt += __shfl_xor(c_cnt, off, 64);
        c_amc += __shfl_xor(c_amc, off, 64);
        imp   += __shfl_xor(imp, off, 64);
      }
      if (lane == 0) { s_cnt[e] = c_cnt; s_amc[e] = c_amc; s_imp[e] = imp; }
    }
    __syncthreads();
    int pad[EXP], start[EXP];
    int o = S_TOK;
#pragma unroll
    for (int j = 0; j < EXP; j++) {
      pad[j] = ((s_cnt[j] + 127) >> 7) << 7;
      start[j] = o;
      o += pad[j];
    }
    const int total = o;
    for (int r = tid; r < S_TOK; r += 512) { pairtok[r] = r; pairw[r] = 1.f; }
    {
      const int e = wv;
      int base = start[e];
      for (int s0 = 0; s0 < S_TOK; s0 += 64) {
        int s = s0 + lane;
        int i0 = tki[2 * s], i1 = tki[2 * s + 1];
        bool m0 = (i0 == e), m1 = (i1 == e);
        bool mm = m0 || m1;
        unsigned long long mk = __ballot(mm);
        if (mm) {
          int pos = base + __popcll(mk & ((1ull << lane) - 1ull));
          pairtok[pos] = s;
          pairw[pos] = m0 ? tkw[2 * s] : tkw[2 * s + 1];
          invmap[2 * s + (m0 ? 0 : 1)] = pos;
        }
        base += __popcll(mk);
      }
      for (int r = base + lane; r < start[e] + pad[e]; r += 64) {
        pairtok[r] = -1; pairw[r] = 0.f;
      }
    }
    if (tid < 128) {
      int ex = 8;
      if (tid >= 32) {
        int rr = tid * 128;
#pragma unroll
        for (int j = 0; j < EXP; j++)
          if (rr >= start[j] && rr < start[j] + pad[j]) ex = j;
      }
      tile_expert[tid] = ex;
    }
    if (tid == 0) {
      meta[0] = total >> 7;
      float a = 0.f;
      for (int j = 0; j < EXP; j++)
        a += (s_imp[j] * (1.f / 4096.f)) * ((float)s_amc[j] * (1.f / 4096.f));
      aux_out[0] = 8.f * a;
    }
    return;
  }
  for (int i = (blockIdx.x - 1) * 512 + threadIdx.x; i < AB_SW2;
       i += (CVTAB_BLKS - 1) * 512) {
    if (i < AB_W1)       cvt4_rowpad(w1,  w1b,  i);
    else if (i < AB_W2)  cvt4_rowpad(w2,  w2b,  i - AB_W1);
    else if (i < AB_SW1) cvt4_rowpad(sw1, sw1b, i - AB_W2);
    else                 cvt4_rowpad(sw2, sw2b, i - AB_SW1);
  }
}

// ---------------- GEMM1: BK=64 single-buffer + w3/sw3 cvt tail blocks ----------
// LDS [128][64] per matrix (48 KB total, 2 blocks/CU). XOR swizzle: physical
// octet = logical ^ (row&7); source pre-swizzled, reads swizzled (rule 21).
// Barrier count halved vs BK=32 (16 K-iters instead of 32).
#define W3CVT_BLKS 1024
#define W3_CHUNKS  (8 * CDIM * CH_CPR)
#define W3TOT      (W3_CHUNKS + CDIM * CH_CPR)

__global__ void __launch_bounds__(256, 2) gemm1_kernel(
    const us* __restrict__ xb, const us* __restrict__ w1b, const us* __restrict__ w2b,
    const us* __restrict__ sw1b, const us* __restrict__ sw2b,
    const int* __restrict__ pairtok, const int* __restrict__ tile_expert,
    const int* __restrict__ meta, us* __restrict__ h,
    const float* __restrict__ w3, const float* __restrict__ sw3,
    us* __restrict__ w3b, us* __restrict__ sw3b) {
  if (blockIdx.x >= G1_BLKS) {
    for (int i = (blockIdx.x - G1_BLKS) * 256 + threadIdx.x; i < W3TOT;
         i += W3CVT_BLKS * 256) {
      if (i < W3_CHUNKS) cvt4_colpad(w3,  w3b,  i);
      else               cvt4_colpad(sw3, sw3b, i - W3_CHUNKS);
    }
    return;
  }
  const int wgid = xcd_swz(blockIdx.x, G1_BLKS);
  const int mt = wgid % MAXTILES;
  if (mt >= meta[0]) return;
  const int n0 = (wgid / MAXTILES) * 128;
  const int e = tile_expert[mt];
  const us* B1 = (e == 8) ? sw1b : (w1b + (size_t)e * HPAD * CDIM);
  const us* B2 = (e == 8) ? sw2b : (w2b + (size_t)e * HPAD * CDIM);
  const int row0 = mt * 128;
  __shared__ __align__(16) us sA[128 * 64];
  __shared__ __align__(16) us sB1[128 * 64];
  __shared__ __align__(16) us sB2[128 * 64];
  const int tid = threadIdx.x, lane = tid & 63;
  const int wm = tid >> 7, wn = (tid >> 6) & 1;
  // staging: instr j covers rows j*32 + (tid>>3); physical octet tid&7 holds
  // logical octet (tid&7) ^ (row&7)
  const int srow = tid >> 3;
  const int soct = (tid & 7) ^ (srow & 7);
  const us* gA[4];
  const us* gB1a[4];
  const us* gB2a[4];
#pragma unroll
  for (int j = 0; j < 4; j++) {
    int t = pairtok[row0 + j * 32 + srow]; if (t < 0) t = 0;
    gA[j]   = xb + (size_t)t * CDIM + soct * 8;
    gB1a[j] = B1 + (size_t)(n0 + j * 32 + srow) * CDIM + soct * 8;
    gB2a[j] = B2 + (size_t)(n0 + j * 32 + srow) * CDIM + soct * 8;
  }
  f32x4 au[4][4], av[4][4];
#pragma unroll
  for (int m = 0; m < 4; m++)
#pragma unroll
    for (int n = 0; n < 4; n++)
#pragma unroll
      for (int r = 0; r < 4; r++) { au[m][n][r] = 0.f; av[m][n][r] = 0.f; }

  const int rl = lane & 15, fo = lane >> 4;
  const int x0 = ((0 + fo) ^ (rl & 7)) << 3;   // ks=0 swizzled slot (elems)
  const int x1 = ((4 + fo) ^ (rl & 7)) << 3;   // ks=1
  for (int k0 = 0; k0 < CDIM; k0 += 64) {
#pragma unroll
    for (int j = 0; j < 4; j++) {
      gl16(gA[j] + k0,   &sA[(j * 256 + tid) * 8]);
      gl16(gB1a[j] + k0, &sB1[(j * 256 + tid) * 8]);
      gl16(gB2a[j] + k0, &sB2[(j * 256 + tid) * 8]);
    }
    __syncthreads();
#pragma unroll
    for (int ks = 0; ks < 2; ks++) {
      const int kx = ks ? x1 : x0;
      bf16x8 a[4], b1[4], b2[4];
#pragma unroll
      for (int m = 0; m < 4; m++)
        a[m] = *(const bf16x8*)&sA[(wm * 64 + m * 16 + rl) * 64 + kx];
#pragma unroll
      for (int n = 0; n < 4; n++) {
        b1[n] = *(const bf16x8*)&sB1[(wn * 64 + n * 16 + rl) * 64 + kx];
        b2[n] = *(const bf16x8*)&sB2[(wn * 64 + n * 16 + rl) * 64 + kx];
      }
#pragma unroll
      for (int m = 0; m < 4; m++)
#pragma unroll
        for (int n = 0; n < 4; n++) {
          au[m][n] = __builtin_amdgcn_mfma_f32_16x16x32_bf16(a[m], b1[n], au[m][n], 0, 0, 0);
          av[m][n] = __builtin_amdgcn_mfma_f32_16x16x32_bf16(a[m], b2[n], av[m][n], 0, 0, 0);
        }
    }
    __syncthreads();
  }
  const int rb = (lane >> 4) * 4, cb = lane & 15;
#pragma unroll
  for (int m = 0; m < 4; m++)
#pragma unroll
    for (int n = 0; n < 4; n++)
#pragma unroll
      for (int r = 0; r < 4; r++) {
        int row = row0 + wm * 64 + m * 16 + rb + r;
        int col = n0 + wn * 64 + n * 16 + cb;
        float u = au[m][n][r], v = av[m][n][r];
        float sg = 1.f / (1.f + __expf(-u));
        h[(size_t)row * HPAD + col] = f2bf(u * sg * v);
      }
}

// ---------------- GEMM2: eo = h @ w3^T, block 128x256, BK=64, bf16 out --------
__global__ void __launch_bounds__(256, 2) gemm2_kernel(
    const us* __restrict__ h, const us* __restrict__ w3b, const us* __restrict__ sw3b,
    const int* __restrict__ tile_expert, const int* __restrict__ meta,
    us* __restrict__ eo) {
  const int wgid = xcd_swz(blockIdx.x, MAXTILES * NSLICE2);
  const int mt = wgid % MAXTILES;
  if (mt >= meta[0]) return;
  const int n0 = (wgid / MAXTILES) * 256;
  const int e = tile_expert[mt];
  const us* B = (e == 8) ? sw3b : (w3b + (size_t)e * CDIM * HPAD);
  const int row0 = mt * 128;
  __shared__ __align__(16) us sA[128 * 64];
  __shared__ __align__(16) us sB[256 * 64];
  const int tid = threadIdx.x, lane = tid & 63;
  const int wm = tid >> 7, wn = (tid >> 6) & 1;
  const int srow = tid >> 3;
  const int soct = (tid & 7) ^ (srow & 7);
  const us* gA[4];
  const us* gB[8];
#pragma unroll
  for (int j = 0; j < 4; j++)
    gA[j] = h + (size_t)(row0 + j * 32 + srow) * HPAD + soct * 8;
#pragma unroll
  for (int j = 0; j < 8; j++)
    gB[j] = B + (size_t)(n0 + j * 32 + srow) * HPAD + soct * 8;
  f32x4 ac[4][8];
#pragma unroll
  for (int m = 0; m < 4; m++)
#pragma unroll
    for (int n = 0; n < 8; n++)
#pragma unroll
      for (int r = 0; r < 4; r++) ac[m][n][r] = 0.f;

  const int rl = lane & 15, fo = lane >> 4;
  const int x0 = ((0 + fo) ^ (rl & 7)) << 3;
  const int x1 = ((4 + fo) ^ (rl & 7)) << 3;
  for (int k0 = 0; k0 < HPAD; k0 += 64) {
#pragma unroll
    for (int j = 0; j < 4; j++)
      gl16(gA[j] + k0, &sA[(j * 256 + tid) * 8]);
#pragma unroll
    for (int j = 0; j < 8; j++)
      gl16(gB[j] + k0, &sB[(j * 256 + tid) * 8]);
    __syncthreads();
#pragma unroll
    for (int ks = 0; ks < 2; ks++) {
      const int kx = ks ? x1 : x0;
      bf16x8 a[4], b[8];
#pragma unroll
      for (int m = 0; m < 4; m++)
        a[m] = *(const bf16x8*)&sA[(wm * 64 + m * 16 + rl) * 64 + kx];
#pragma unroll
      for (int n = 0; n < 8; n++)
        b[n] = *(const bf16x8*)&sB[(wn * 128 + n * 16 + rl) * 64 + kx];
#pragma unroll
      for (int m = 0; m < 4; m++)
#pragma unroll
        for (int n = 0; n < 8; n++)
          ac[m][n] = __builtin_amdgcn_mfma_f32_16x16x32_bf16(a[m], b[n], ac[m][n], 0, 0, 0);
    }
    __syncthreads();
  }
  const int rb = (lane >> 4) * 4, cb = lane & 15;
#pragma unroll
  for (int m = 0; m < 4; m++)
#pragma unroll
    for (int n = 0; n < 8; n++)
#pragma unroll
      for (int r = 0; r < 4; r++) {
        int row = row0 + wm * 64 + m * 16 + rb + r;
        int col = n0 + wn * 128 + n * 16 + cb;
        eo[(size_t)row * CDIM + col] = f2bf(ac[m][n][r]);
      }
}

// ---------------- combine (bf16 eo) ----------------
__global__ void __launch_bounds__(256) combine_kernel(const us* __restrict__ eo,
                                                      const int* __restrict__ invmap,
                                                      const float* __restrict__ pairw,
                                                      float* __restrict__ out) {
  const int s = blockIdx.x;
  const int c = threadIdx.x * 4;
  const int j0 = invmap[2 * s], j1 = invmap[2 * s + 1];
  const float w0 = pairw[j0], w1 = pairw[j1];
  us4 a = *(const us4*)(eo + (size_t)s * CDIM + c);
  us4 b = *(const us4*)(eo + (size_t)j0 * CDIM + c);
  us4 d = *(const us4*)(eo + (size_t)j1 * CDIM + c);
  float4 o;
  o.x = bf2f(a.x) + w0 * bf2f(b.x) + w1 * bf2f(d.x);
  o.y = bf2f(a.y) + w0 * bf2f(b.y) + w1 * bf2f(d.y);
  o.z = bf2f(a.z) + w0 * bf2f(b.z) + w1 * bf2f(d.z);
  o.w = bf2f(a.w) + w0 * bf2f(b.w) + w1 * bf2f(d.w);
  *(float4*)(out + (size_t)s * CDIM + c) = o;
}

extern "C" void kernel_launch(void* const* d_in, const int* in_sizes, int n_in,
                              void* d_out, int out_size, void* d_ws, size_t ws_size,
                              hipStream_t stream) {
  const float* x   = (const float*)d_in[0];
  const float* gw  = (const float*)d_in[1];
  const float* w1  = (const float*)d_in[2];
  const float* w2  = (const float*)d_in[3];
  const float* w3  = (const float*)d_in[4];
  const float* sw1 = (const float*)d_in[5];
  const float* sw2 = (const float*)d_in[6];
  const float* sw3 = (const float*)d_in[7];
  float* out = (float*)d_out;
  char* ws = (char*)d_ws;
  size_t off = 0;
  auto take = [&](size_t bytes) -> char* {
    char* p = ws + off;
    off = (off + bytes + 255) & ~(size_t)255;
    return p;
  };
  us* xb    = (us*)take((size_t)S_TOK * CDIM * 2);
  us* w1b   = (us*)take((size_t)EXP * HPAD * CDIM * 2);
  us* w2b   = (us*)take((size_t)EXP * HPAD * CDIM * 2);
  us* w3b   = (us*)take((size_t)EXP * CDIM * HPAD * 2);
  us* sw1b  = (us*)take((size_t)HPAD * CDIM * 2);
  us* sw2b  = (us*)take((size_t)HPAD * CDIM * 2);
  us* sw3b  = (us*)take((size_t)CDIM * HPAD * 2);
  us* hbuf  = (us*)take((size_t)MAXROWS * HPAD * 2);
  us* eo    = (us*)take((size_t)MAXROWS * CDIM * 2);   // bf16 expert outputs
  int* pairtok = (int*)take(MAXROWS * 4);
  float* pairw = (float*)take(MAXROWS * 4);
  int* invmap  = (int*)take(S_TOK * 2 * 4);
  int* tile_expert = (int*)take(128 * 4);
  int* tki = (int*)take(S_TOK * 2 * 4);
  float* tkw = (float*)take(S_TOK * 2 * 4);
  float* probs = (float*)take(S_TOK * EXP * 4);
  int* meta = (int*)take(256);
  if (off > ws_size) {
    fprintf(stderr, "MoE kernel: ws too small, need %zu got %zu\n", off, ws_size);
    return;
  }
  gate_kernel<<<S_TOK / 4, 256, 0, stream>>>(x, gw, xb, tki, tkw, probs);
  cvtab_build_kernel<<<CVTAB_BLKS, 512, 0, stream>>>(
      w1, w2, sw1, sw2, w1b, w2b, sw1b, sw2b,
      tki, tkw, probs, meta, pairtok, pairw, invmap, tile_expert,
      out + (size_t)S_TOK * CDIM);
  gemm1_kernel<<<G1_BLKS + W3CVT_BLKS, 256, 0, stream>>>(
      xb, w1b, w2b, sw1b, sw2b, pairtok, tile_expert, meta, hbuf,
      w3, sw3, w3b, sw3b);
  gemm2_kernel<<<MAXTILES * NSLICE2, 256, 0, stream>>>(
      hbuf, w3b, sw3b, tile_expert, meta, eo);
  combine_kernel<<<S_TOK, 256, 0, stream>>>(eo, invmap, pairw, out);
}